// Round 8
// baseline (231.177 us; speedup 1.0000x reference)
//
#include <hip/hip_runtime.h>

#define NN 50000
#define EE 200000
#define RR 4
#define SC_TOTAL (RR * NN)                 // 200000 segments
#define CAP 32                             // max in-degree per (node,etype); P(exceed)~1e-19
#define GTILE ((NN + 127) / 128)           // 391 row-tiles of 128 for gemm1
#define NB_G1 (4 * GTILE)                  // 1564 gemm1 tiles (512 cols)
#define NB_F  1563                         // fill chunks (512 edges each, 2/thread)

typedef __attribute__((ext_vector_type(8))) short bf16x8;
typedef __attribute__((ext_vector_type(4))) float f32x4;

__device__ inline unsigned short f2bf(float x) {   // round-to-nearest-even
    unsigned int u = __float_as_uint(x);
    u += 0x7fffu + ((u >> 16) & 1u);
    return (unsigned short)(u >> 16);
}
__device__ inline float bflo(unsigned u) { return __uint_as_float(u << 16); }
__device__ inline float bfhi(unsigned u) { return __uint_as_float(u & 0xffff0000u); }

// ---------------------------------------------------------------------------
// init (block-range partitioned): featb [0,6250) | W1T [6250,6506) |
// W2T [6506,6634) | btab1 [6634,6642) | btab2 [6642,6646) |
// cnt zero [6646,6842).
// W layouts are TRANSFORM-FIRST concat: WT[jout][k], jout = r*ON + j.
__global__ __launch_bounds__(256) void init_kernel(
    const float* __restrict__ feat, unsigned short* __restrict__ featb,
    const float* __restrict__ W1, const float* __restrict__ b1,
    const float* __restrict__ W2, const float* __restrict__ b2,
    unsigned short* __restrict__ W1T, unsigned short* __restrict__ W2T,
    float* __restrict__ btab1, float* __restrict__ btab2,
    int* __restrict__ cnt)
{
    int b = blockIdx.x, t = threadIdx.x;
    if (b < 6250) {
        int i = (b * 256 + t) * 4;
        float4 v = *(const float4*)&feat[i];
        unsigned lo = (unsigned)f2bf(v.x) | ((unsigned)f2bf(v.y) << 16);
        unsigned hi = (unsigned)f2bf(v.z) | ((unsigned)f2bf(v.w) << 16);
        *(uint2*)&featb[i] = make_uint2(lo, hi);
    } else if (b < 6506) {
        // W1T[(r*128+j)*128 + k] = W1[r,k,j];  i in [0,65536)
        int i = (b - 6250) * 256 + t;
        int jout = i >> 7, k = i & 127;
        int r = jout >> 7, j = jout & 127;
        W1T[i] = f2bf(W1[r * 16384 + k * 128 + j]);
    } else if (b < 6634) {
        // W2T[(r*64+j)*128 + k] = W2[r,k,j];  i in [0,32768)
        int i = (b - 6506) * 256 + t;
        int jout = i >> 7, k = i & 127;
        int r = jout >> 6, j = jout & 63;
        W2T[i] = f2bf(W2[r * 8192 + k * 64 + j]);
    } else if (b < 6642) {
        int i = (b - 6634) * 256 + t;
        int mm = i >> 7, c = i & 127;
        float s = 0.f;
        #pragma unroll
        for (int r = 0; r < RR; ++r) if (mm & (1 << r)) s += b1[r * 128 + c];
        btab1[i] = s;
    } else if (b < 6646) {
        int i = (b - 6642) * 256 + t;
        int mm = i >> 6, c = i & 63;
        float s = 0.f;
        #pragma unroll
        for (int r = 0; r < RR; ++r) if (mm & (1 << r)) s += b2[r * 64 + c];
        btab2[i] = s;
    } else {
        // zero cnt: 200K ints, int4 per thread
        int i = ((b - 6646) * 256 + t) * 4;
        if (i < SC_TOTAL) *(int4*)&cnt[i] = make_int4(0, 0, 0, 0);
    }
}

// ---------------------------------------------------------------------------
// FUSED fill + gemm1. Even blocks: one 128x128 tile of H1 = featb @ W1cat.
// Odd blocks: 512-edge bucket-append chunk (TCC-bound). 1:1 interleave.
__global__ __launch_bounds__(256) void fill_gemm1(
    const int* __restrict__ edges, int* __restrict__ cnt,
    unsigned short* __restrict__ ssrc2,
    const unsigned short* __restrict__ A, const unsigned short* __restrict__ WT,
    unsigned short* __restrict__ H)
{
    __shared__ __align__(16) unsigned short Wl[128 * 128];   // 32768 B (gemm path)
    const int bid = blockIdx.x;
    const int tid = threadIdx.x;

    if (bid & 1) {
        // ---- fill path: f in [0, NB_F), 2 edges/thread (independent chains)
        int f = bid >> 1;
        #pragma unroll
        for (int k = 0; k < 2; ++k) {
            int i = f * 512 + k * 256 + tid;
            if (i < RR * EE) {
                int r = i / EE;
                int e = i - r * EE;
                const int* es = edges + (size_t)r * 2 * EE;
                int src = es[e];
                int dst = es[EE + e];
                int seg = r * NN + dst;
                int p = atomicAdd(&cnt[seg], 1);
                if (p < CAP) ssrc2[(size_t)seg * CAP + p] = (unsigned short)src;
            }
        }
        return;
    }

    // ---- gemm path: g in [0, NB_G1); tile (col0, row0), OTOT=512
    const int g    = bid >> 1;
    const int wv   = tid >> 6;
    const int lane = tid & 63;
    const int m    = lane & 15;
    const int q    = lane >> 4;
    const int col0 = (g & 3) * 128;
    const int row0 = (g >> 2) * 128;

    // stage W panel once: linear global read, swizzled LDS write
    #pragma unroll
    for (int i = 0; i < 8; ++i) {
        int L  = i * 4096 + tid * 16;       // linear byte in [128][256]
        int nr = L >> 8, ir = L & 255;
        uint4 v = *(const uint4*)((const char*)WT + ((size_t)(col0 + nr) << 8) + ir);
        *(uint4*)((char*)Wl + nr * 256 + (ir ^ ((nr & 7) << 4))) = v;
    }
    __syncthreads();

    f32x4 acc[2][8];
    #pragma unroll
    for (int rf = 0; rf < 2; ++rf)
        #pragma unroll
        for (int nt = 0; nt < 8; ++nt) acc[rf][nt] = (f32x4){0.f, 0.f, 0.f, 0.f};

    const int ra0 = row0 + wv * 32 + m;
    const int ra1 = ra0 + 16;
    const bool g0 = ra0 < NN, g1 = ra1 < NN;
    const unsigned short* Ap0 = A + (size_t)ra0 * 128 + q * 8;
    const unsigned short* Ap1 = A + (size_t)ra1 * 128 + q * 8;
    const bf16x8 bz = (bf16x8){0, 0, 0, 0, 0, 0, 0, 0};

    #pragma unroll
    for (int kk = 0; kk < 4; ++kk) {
        bf16x8 a0 = g0 ? *(const bf16x8*)(Ap0 + kk * 32) : bz;
        bf16x8 a1 = g1 ? *(const bf16x8*)(Ap1 + kk * 32) : bz;
        #pragma unroll
        for (int nt = 0; nt < 8; ++nt) {
            int offb = (nt * 16 + m) * 256 + ((kk * 64 + q * 16) ^ ((m & 7) << 4));
            bf16x8 bfr = *(const bf16x8*)((const char*)Wl + offb);
            acc[0][nt] = __builtin_amdgcn_mfma_f32_16x16x32_bf16(a0, bfr, acc[0][nt], 0, 0, 0);
            acc[1][nt] = __builtin_amdgcn_mfma_f32_16x16x32_bf16(a1, bfr, acc[1][nt], 0, 0, 0);
        }
    }

    #pragma unroll
    for (int rf = 0; rf < 2; ++rf) {
        #pragma unroll
        for (int rg = 0; rg < 4; ++rg) {
            int row = row0 + wv * 32 + rf * 16 + q * 4 + rg;
            if (row < NN) {
                unsigned short* Hp = H + (size_t)row * 512 + col0 + m;
                #pragma unroll
                for (int nt = 0; nt < 8; ++nt)
                    Hp[nt * 16] = f2bf(acc[rf][nt][rg]);
            }
        }
    }
}

// ---------------------------------------------------------------------------
// FUSED gather1 + gemm2: block = 64 nodes. Lane (m,q) of wave wv gathers node
// n = n0+wv*16+m, cols {kk*32+q*8..+8} (= exactly its MFMA A-fragment slots),
// applies btab1+relu, converts to bf16 frags, then MFMAs against W2cat read
// DIRECTLY from L2 (64 KB, resident) -> H2 [N,256] (SEPARATE buffer — the
// round-7 in-place aliasing was a cross-block race). No LDS, no barriers.
__global__ __launch_bounds__(256) void gather_gemm2(
    const unsigned short* __restrict__ H1, const unsigned short* __restrict__ ssrc2,
    const int* __restrict__ cnt, const float* __restrict__ btab1,
    const unsigned short* __restrict__ W2T, unsigned short* __restrict__ H2)
{
    const int tid  = threadIdx.x;
    const int wv   = tid >> 6;
    const int lane = tid & 63;
    const int m    = lane & 15;
    const int q    = lane >> 4;
    const int n0   = blockIdx.x * 64;
    const int n    = n0 + wv * 16 + m;      // gather row (A row m of this wave)

    float tot[32];
    #pragma unroll
    for (int i = 0; i < 32; ++i) tot[i] = 0.f;
    int mk = 0;

    if (n < NN) {
        int   dg[RR];
        uint4 id[RR];
        #pragma unroll
        for (int r = 0; r < RR; ++r) {
            int seg = r * NN + n;
            dg[r] = cnt[seg];
            id[r] = *(const uint4*)(ssrc2 + (size_t)seg * CAP);
        }
        #pragma unroll
        for (int r = 0; r < RR; ++r) {
            if (dg[r] > 0) {
                mk |= 1 << r;
                int nd = dg[r] < CAP ? dg[r] : CAP;
                float tmp[32];
                #pragma unroll
                for (int i = 0; i < 32; ++i) tmp[i] = 0.f;
                // first 8 edges from preloaded indices: 8j x 4kk = 32 indep loads
                #pragma unroll
                for (int j = 0; j < 8; ++j) {
                    if (j < nd) {
                        unsigned w = (j >> 1) == 0 ? id[r].x : (j >> 1) == 1 ? id[r].y
                                   : (j >> 1) == 2 ? id[r].z : id[r].w;
                        unsigned s = (j & 1) ? (w >> 16) : (w & 0xffffu);
                        const unsigned short* row = H1 + (size_t)s * 512 + r * 128 + q * 8;
                        #pragma unroll
                        for (int kk = 0; kk < 4; ++kk) {
                            uint4 u = *(const uint4*)(row + kk * 32);
                            tmp[kk*8+0] += bflo(u.x); tmp[kk*8+1] += bfhi(u.x);
                            tmp[kk*8+2] += bflo(u.y); tmp[kk*8+3] += bfhi(u.y);
                            tmp[kk*8+4] += bflo(u.z); tmp[kk*8+5] += bfhi(u.z);
                            tmp[kk*8+6] += bflo(u.w); tmp[kk*8+7] += bfhi(u.w);
                        }
                    }
                }
                // rare tail (deg > 8)
                for (int j = 8; j < nd; ++j) {
                    unsigned s = ssrc2[(size_t)(r * NN + n) * CAP + j];
                    const unsigned short* row = H1 + (size_t)s * 512 + r * 128 + q * 8;
                    #pragma unroll
                    for (int kk = 0; kk < 4; ++kk) {
                        uint4 u = *(const uint4*)(row + kk * 32);
                        tmp[kk*8+0] += bflo(u.x); tmp[kk*8+1] += bfhi(u.x);
                        tmp[kk*8+2] += bflo(u.y); tmp[kk*8+3] += bfhi(u.y);
                        tmp[kk*8+4] += bflo(u.z); tmp[kk*8+5] += bfhi(u.z);
                        tmp[kk*8+6] += bflo(u.w); tmp[kk*8+7] += bfhi(u.w);
                    }
                }
                float iv = 1.0f / (float)dg[r];
                #pragma unroll
                for (int i = 0; i < 32; ++i) tot[i] += tmp[i] * iv;
            }
        }
    }

    // bias + relu + bf16 convert -> A-fragments (h1 row n, identical numerics
    // to the old h1r path: fp32 accum, +btab, relu, rne round)
    const float* bt = btab1 + mk * 128 + q * 8;
    bf16x8 af[4];
    #pragma unroll
    for (int kk = 0; kk < 4; ++kk) {
        float4 t0 = *(const float4*)(bt + kk * 32);
        float4 t1 = *(const float4*)(bt + kk * 32 + 4);
        bf16x8 a;
        a[0] = (short)f2bf(fmaxf(tot[kk*8+0] + t0.x, 0.f));
        a[1] = (short)f2bf(fmaxf(tot[kk*8+1] + t0.y, 0.f));
        a[2] = (short)f2bf(fmaxf(tot[kk*8+2] + t0.z, 0.f));
        a[3] = (short)f2bf(fmaxf(tot[kk*8+3] + t0.w, 0.f));
        a[4] = (short)f2bf(fmaxf(tot[kk*8+4] + t1.x, 0.f));
        a[5] = (short)f2bf(fmaxf(tot[kk*8+5] + t1.y, 0.f));
        a[6] = (short)f2bf(fmaxf(tot[kk*8+6] + t1.z, 0.f));
        a[7] = (short)f2bf(fmaxf(tot[kk*8+7] + t1.w, 0.f));
        af[kk] = a;
    }

    // MFMA: 64x256 = A(64x128) @ W2cat^T; B-frags straight from L2
    f32x4 acc[16];
    #pragma unroll
    for (int nt = 0; nt < 16; ++nt) acc[nt] = (f32x4){0.f, 0.f, 0.f, 0.f};
    #pragma unroll
    for (int kk = 0; kk < 4; ++kk) {
        #pragma unroll
        for (int nt = 0; nt < 16; ++nt) {
            bf16x8 bfr = *(const bf16x8*)(W2T + (size_t)(nt * 16 + m) * 128 + kk * 32 + q * 8);
            acc[nt] = __builtin_amdgcn_mfma_f32_16x16x32_bf16(af[kk], bfr, acc[nt], 0, 0, 0);
        }
    }

    // epilogue: C row = q*4+rg (lane mapping differs from gather mapping)
    #pragma unroll
    for (int rg = 0; rg < 4; ++rg) {
        int row = n0 + wv * 16 + q * 4 + rg;
        if (row < NN) {
            unsigned short* Hp = H2 + (size_t)row * 256 + m;
            #pragma unroll
            for (int nt = 0; nt < 16; ++nt)
                Hp[nt * 16] = f2bf(acc[nt][rg]);
        }
    }
}

// ---------------------------------------------------------------------------
// gather-mean layer 2, MLP-boosted: 8 lanes/node, 128B rows (r*64 cols);
// idx preload as uint4; sum across etypes + btab2[mk] -> out [N,64] fp32.
__global__ __launch_bounds__(256) void gather_node2(
    const unsigned short* __restrict__ H2, const unsigned short* __restrict__ ssrc2,
    const int* __restrict__ cnt, const float* __restrict__ btab2,
    float* __restrict__ out)
{
    int n = blockIdx.x * 32 + (threadIdx.x >> 3);
    if (n >= NN) return;
    int l = threadIdx.x & 7;

    int   dg[RR];
    uint4 id[RR];
    #pragma unroll
    for (int r = 0; r < RR; ++r) {
        int seg = r * NN + n;
        dg[r] = cnt[seg];
        id[r] = *(const uint4*)(ssrc2 + (size_t)seg * CAP);
    }

    float ac[RR][8];
    #pragma unroll
    for (int r = 0; r < RR; ++r)
        #pragma unroll
        for (int i = 0; i < 8; ++i) ac[r][i] = 0.f;

    #pragma unroll
    for (int j = 0; j < 8; ++j) {
        #pragma unroll
        for (int r = 0; r < RR; ++r) {
            if (j < dg[r]) {
                unsigned w = (j >> 1) == 0 ? id[r].x : (j >> 1) == 1 ? id[r].y
                           : (j >> 1) == 2 ? id[r].z : id[r].w;
                unsigned s = (j & 1) ? (w >> 16) : (w & 0xffffu);
                uint4 u = *(const uint4*)(H2 + r * 64 + l * 8 + (size_t)s * 256);
                ac[r][0] += bflo(u.x); ac[r][1] += bfhi(u.x);
                ac[r][2] += bflo(u.y); ac[r][3] += bfhi(u.y);
                ac[r][4] += bflo(u.z); ac[r][5] += bfhi(u.z);
                ac[r][6] += bflo(u.w); ac[r][7] += bfhi(u.w);
            }
        }
    }
    if ((dg[0] | dg[1] | dg[2] | dg[3]) > 8) {
        #pragma unroll
        for (int r = 0; r < RR; ++r) {
            int nd = dg[r] < CAP ? dg[r] : CAP;
            for (int j = 8; j < nd; ++j) {
                unsigned s = ssrc2[(size_t)(r * NN + n) * CAP + j];
                uint4 u = *(const uint4*)(H2 + r * 64 + l * 8 + (size_t)s * 256);
                ac[r][0] += bflo(u.x); ac[r][1] += bfhi(u.x);
                ac[r][2] += bflo(u.y); ac[r][3] += bfhi(u.y);
                ac[r][4] += bflo(u.z); ac[r][5] += bfhi(u.z);
                ac[r][6] += bflo(u.w); ac[r][7] += bfhi(u.w);
            }
        }
    }

    int mk = (dg[0] > 0 ? 1 : 0) | (dg[1] > 0 ? 2 : 0) |
             (dg[2] > 0 ? 4 : 0) | (dg[3] > 0 ? 8 : 0);
    float iv[RR];
    #pragma unroll
    for (int r = 0; r < RR; ++r) iv[r] = dg[r] > 0 ? 1.0f / (float)dg[r] : 0.f;

    const float* bt = btab2 + mk * 64 + l * 8;
    float4 t0 = *(const float4*)bt;
    float4 t1 = *(const float4*)(bt + 4);
    float o0[8] = {t0.x, t0.y, t0.z, t0.w, t1.x, t1.y, t1.z, t1.w};
    #pragma unroll
    for (int i = 0; i < 8; ++i)
        #pragma unroll
        for (int r = 0; r < RR; ++r) o0[i] += ac[r][i] * iv[r];

    float* op = out + (size_t)n * 64 + l * 8;
    *(float4*)op       = make_float4(o0[0], o0[1], o0[2], o0[3]);
    *(float4*)(op + 4) = make_float4(o0[4], o0[5], o0[6], o0[7]);
}

// ---------------------------------------------------------------------------
extern "C" void kernel_launch(void* const* d_in, const int* in_sizes, int n_in,
                              void* d_out, int out_size, void* d_ws, size_t ws_size,
                              hipStream_t stream)
{
    const float* feat  = (const float*)d_in[0];   // [N,128]
    const float* W1    = (const float*)d_in[1];   // [R,128,128]
    const float* b1    = (const float*)d_in[2];   // [R,128]
    const float* W2    = (const float*)d_in[3];   // [R,128,64]
    const float* b2    = (const float*)d_in[4];   // [R,64]
    const int*   edges = (const int*)d_in[5];     // [R,2,E]
    float* out = (float*)d_out;                   // [N,64] fp32

    char* p = (char*)d_ws;
    auto alloc = [&](size_t bytes) { char* q = p; p += (bytes + 255) & ~(size_t)255; return q; };
    int* cnt                 = (int*)alloc((size_t)SC_TOTAL * 4);                  // 0.8MB
    unsigned short* ssrc2    = (unsigned short*)alloc((size_t)SC_TOTAL * CAP * 2); // 12.8MB
    unsigned short* W1T      = (unsigned short*)alloc((size_t)512 * 128 * 2);
    unsigned short* W2T      = (unsigned short*)alloc((size_t)256 * 128 * 2);
    float* btab1             = (float*)alloc((size_t)16 * 128 * 4);
    float* btab2             = (float*)alloc((size_t)16 * 64 * 4);
    unsigned short* featb    = (unsigned short*)alloc((size_t)NN * 128 * 2);   // 12.8MB
    unsigned short* H        = (unsigned short*)alloc((size_t)NN * 512 * 2);   // 51.2MB (H1)
    unsigned short* H2       = (unsigned short*)alloc((size_t)NN * 256 * 2);   // 25.6MB (H2, separate!)

    // 1: featb + weight prep + zero cnt
    init_kernel<<<6842, 256, 0, stream>>>(feat, featb, W1, b1, W2, b2,
                                          W1T, W2T, btab1, btab2, cnt);
    // 2: FUSED bucket-append (odd blocks) + H1 = featb @ W1cat (even blocks)
    fill_gemm1<<<NB_G1 + NB_F, 256, 0, stream>>>(edges, cnt, ssrc2, featb, W1T, H);
    // 3: FUSED h1 = relu(mean+bias)  ->  H2 = h1 @ W2cat   [N,256]
    gather_gemm2<<<(NN + 63) / 64, 256, 0, stream>>>(H, ssrc2, cnt, btab1, W2T, H2);
    // 4: out = sum_r mean_r(H2 slices) + btab2[mk]  [N,64] fp32
    gather_node2<<<(NN + 31) / 32, 256, 0, stream>>>(H2, ssrc2, cnt, btab2, out);
}